// Round 1
// baseline (199.997 us; speedup 1.0000x reference)
//
#include <hip/hip_runtime.h>
#include <stdint.h>

#define Bsz 128
#define Tn  512
#define In  700
#define On  128
#define Mn  (Bsz * Tn)   // 65536
#define KP  704          // K padded to multiple of 32

using bf16x8 = __attribute__((ext_vector_type(8))) short;
using f32x4  = __attribute__((ext_vector_type(4))) float;

__device__ __forceinline__ uint32_t f2bf(float f) {
  union { float f; uint32_t u; } v; v.f = f;
  return (v.u + 0x7fffu + ((v.u >> 16) & 1u)) >> 16;   // RNE
}
__device__ __forceinline__ int pack2(float a, float b) {
  return (int)(f2bf(a) | (f2bf(b) << 16));
}

// ---- prep: w (700x128 f32, k-major) -> w_t (128 x 704 bf16, zero-padded K) ----
__global__ void prep_wt(const float* __restrict__ w, ushort* __restrict__ w_t) {
  int idx = blockIdx.x * 256 + threadIdx.x;
  if (idx >= On * KP) return;
  int col = idx / KP, k = idx - col * KP;
  float v = (k < In) ? w[(size_t)k * On + col] : 0.0f;
  w_t[(size_t)col * KP + k] = (ushort)f2bf(v);
}

// ---- GEMM: h[m][n] = sum_k A[m][k] * w[k][n], bf16 MFMA, BM=128 BN=128 BK=32 ----
__global__ __launch_bounds__(256) void gemm_h(
    const float* __restrict__ A,    // 65536 x 700 f32
    const ushort* __restrict__ Wt,  // 128 x 704 bf16 (transposed w)
    float* __restrict__ H)          // 65536 x 128 f32
{
  __shared__ int4 As[512];  // 128 rows x 4 kb-slots x 16B (bf16), XOR-swizzled
  __shared__ int4 Bs[512];  // 128 cols x 4 kb-slots x 16B

  const int tid  = threadIdx.x;
  const int bm   = blockIdx.x;       // 512 blocks over M
  const int lane = tid & 63;
  const int wid  = tid >> 6;         // 4 waves: 2x2 wave grid, 64x64 each
  const int wm   = wid >> 1, wn = wid & 1;
  const int l16  = lane & 15, lkb = lane >> 4;
  const int kbA  = lkb ^ ((l16 >> 2) & 3);   // swizzled kb for frag reads

  f32x4 acc[4][4];
#pragma unroll
  for (int i = 0; i < 4; ++i)
#pragma unroll
    for (int n = 0; n < 4; ++n) acc[i][n] = (f32x4){0.f, 0.f, 0.f, 0.f};

  const int sRow0 = tid >> 2;        // staging: idx -> (row, kb)
  const int sKb   = tid & 3;
  const int sRow1 = sRow0 + 64;      // (tid+256)>>2

  for (int kt = 0; kt < 22; ++kt) {
    const int k0 = kt * 32;

    // ---- stage A tile (fp32 -> bf16, 2 slots of 16B per thread) ----
#pragma unroll
    for (int i = 0; i < 2; ++i) {
      const int row = (i == 0) ? sRow0 : sRow1;
      const int gk  = k0 + sKb * 8;
      float4 f0 = {0, 0, 0, 0}, f1 = {0, 0, 0, 0};
      const float* ap = A + (size_t)(bm * 128 + row) * 700 + gk;
      if (gk + 4 <= 700) f0 = *reinterpret_cast<const float4*>(ap);
      if (gk + 8 <= 700) f1 = *reinterpret_cast<const float4*>(ap + 4);
      int4 pk;
      pk.x = pack2(f0.x, f0.y); pk.y = pack2(f0.z, f0.w);
      pk.z = pack2(f1.x, f1.y); pk.w = pack2(f1.z, f1.w);
      As[row * 4 + (sKb ^ ((row >> 2) & 3))] = pk;
    }
    // ---- stage B^T tile (already bf16, 2 x 16B per thread) ----
#pragma unroll
    for (int i = 0; i < 2; ++i) {
      const int col = (i == 0) ? sRow0 : sRow1;
      const int4 v = *reinterpret_cast<const int4*>(Wt + (size_t)col * KP + k0 + sKb * 8);
      Bs[col * 4 + (sKb ^ ((col >> 2) & 3))] = v;
    }
    __syncthreads();

    // ---- fragments + MFMA ----
    bf16x8 af[4], bfr[4];
#pragma unroll
    for (int i = 0; i < 4; ++i) {
      const int row = wm * 64 + i * 16 + l16;
      af[i] = *reinterpret_cast<const bf16x8*>(&As[row * 4 + kbA]);
    }
#pragma unroll
    for (int n = 0; n < 4; ++n) {
      const int col = wn * 64 + n * 16 + l16;
      bfr[n] = *reinterpret_cast<const bf16x8*>(&Bs[col * 4 + kbA]);
    }
#pragma unroll
    for (int i = 0; i < 4; ++i)
#pragma unroll
      for (int n = 0; n < 4; ++n)
        acc[i][n] = __builtin_amdgcn_mfma_f32_16x16x32_bf16(af[i], bfr[n], acc[i][n], 0, 0, 0);
    __syncthreads();
  }

  // ---- epilogue: D row = (lane>>4)*4 + reg, col = lane&15 ----
  const int rbase = bm * 128 + wm * 64 + lkb * 4;
#pragma unroll
  for (int i = 0; i < 4; ++i) {
#pragma unroll
    for (int n = 0; n < 4; ++n) {
      const int gcol = wn * 64 + n * 16 + l16;
#pragma unroll
      for (int r = 0; r < 4; ++r)
        H[(size_t)(rbase + i * 16 + r) * 128 + gcol] = acc[i][n][r];
    }
  }
}

// ---- scan over T (sequential), in-place over h in the syn region ----
// S_0 = 0, M_0 = 0 ; S_t = a*S_{t-1} + h[t-1] ; M_t = b*M_{t-1} + (1-b)*S_{t-1}
__global__ __launch_bounds__(64) void scan_k(
    float* __restrict__ syn, float* __restrict__ mem,
    const float* __restrict__ alpha, const float* __restrict__ beta)
{
  const int b = blockIdx.x >> 1;
  const int o = ((blockIdx.x & 1) << 6) + threadIdx.x;
  const float a   = alpha[o];
  const float bt  = beta[o];
  const float omb = 1.0f - bt;
  float* hp = syn + (size_t)b * Tn * On + o;   // holds h, overwritten with S
  float* mp = mem + (size_t)b * Tn * On + o;
  float S = 0.f, M = 0.f;
  float buf[8];
#pragma unroll
  for (int d = 0; d < 8; ++d) buf[d] = hp[d * On];   // prefetch h[0..7]
  for (int tb = 0; tb < Tn; tb += 8) {
#pragma unroll
    for (int d = 0; d < 8; ++d) {
      const int t = tb + d;
      const float h_t = buf[d];
      if (t + 8 < Tn) buf[d] = hp[(t + 8) * On];     // prefetch ahead (static idx)
      hp[t * On] = S;                                 // overwrite h[t] (already consumed)
      mp[t * On] = M;
      const float nS = fmaf(a, S, h_t);
      M = fmaf(bt, M, omb * S);
      S = nS;
    }
  }
}

extern "C" void kernel_launch(void* const* d_in, const int* in_sizes, int n_in,
                              void* d_out, int out_size, void* d_ws, size_t ws_size,
                              hipStream_t stream) {
  const float* inputs = (const float*)d_in[0];   // (128,512,700)
  const float* w      = (const float*)d_in[1];   // (700,128)
  const float* alpha  = (const float*)d_in[2];   // (1,128)
  const float* beta   = (const float*)d_in[3];   // (1,128)

  float* syn = (float*)d_out;                    // first 8M floats
  float* mem = syn + (size_t)Bsz * Tn * On;      // next 8M floats
  ushort* w_t = (ushort*)mem;                    // 180 KB temp in mem region,
                                                 // consumed by gemm before scan overwrites

  prep_wt<<<(On * KP + 255) / 256, 256, 0, stream>>>(w, w_t);
  gemm_h<<<Mn / 128, 256, 0, stream>>>(inputs, w_t, syn);
  scan_k<<<Bsz * 2, 64, 0, stream>>>(syn, mem, alpha, beta);
}

// Round 2
// 78.891 us; speedup vs baseline: 2.5351x; 2.5351x over previous
//
#include <hip/hip_runtime.h>
#include <stdint.h>

#define Bsz 128
#define Tn  512
#define In  700
#define On  128
#define Mn  (Bsz * Tn)   // 65536
#define KP  704          // K padded to multiple of 32
#define NSEG 16
#define LSEG 32          // Tn / NSEG
#define BO   (Bsz * On)  // 16384 chains

using bf16x8 = __attribute__((ext_vector_type(8))) short;
using f32x4  = __attribute__((ext_vector_type(4))) float;

__device__ __forceinline__ uint32_t f2bf(float f) {
  union { float f; uint32_t u; } v; v.f = f;
  return (v.u + 0x7fffu + ((v.u >> 16) & 1u)) >> 16;   // RNE
}
__device__ __forceinline__ int pack2(float a, float b) {
  return (int)(f2bf(a) | (f2bf(b) << 16));
}

// ---- prep: w (700x128 f32, k-major) -> w_t (128 x 704 bf16, zero-padded K) ----
__global__ void prep_wt(const float* __restrict__ w, ushort* __restrict__ w_t) {
  int idx = blockIdx.x * 256 + threadIdx.x;
  if (idx >= On * KP) return;
  int col = idx / KP, k = idx - col * KP;
  float v = (k < In) ? w[(size_t)k * On + col] : 0.0f;
  w_t[(size_t)col * KP + k] = (ushort)f2bf(v);
}

// ---- GEMM: h[m][n] = sum_k A[m][k] * w[k][n], bf16 MFMA, BM=128 BN=128 BK=32 ----
__global__ __launch_bounds__(256) void gemm_h(
    const float* __restrict__ A,    // 65536 x 700 f32
    const ushort* __restrict__ Wt,  // 128 x 704 bf16 (transposed w)
    float* __restrict__ H)          // 65536 x 128 f32
{
  __shared__ int4 As[512];  // 128 rows x 4 kb-slots x 16B (bf16), XOR-swizzled
  __shared__ int4 Bs[512];  // 128 cols x 4 kb-slots x 16B

  const int tid  = threadIdx.x;
  const int bm   = blockIdx.x;       // 512 blocks over M
  const int lane = tid & 63;
  const int wid  = tid >> 6;         // 4 waves: 2x2 wave grid, 64x64 each
  const int wm   = wid >> 1, wn = wid & 1;
  const int l16  = lane & 15, lkb = lane >> 4;
  const int kbA  = lkb ^ ((l16 >> 2) & 3);   // swizzled kb for frag reads

  f32x4 acc[4][4];
#pragma unroll
  for (int i = 0; i < 4; ++i)
#pragma unroll
    for (int n = 0; n < 4; ++n) acc[i][n] = (f32x4){0.f, 0.f, 0.f, 0.f};

  const int sRow0 = tid >> 2;        // staging: idx -> (row, kb)
  const int sKb   = tid & 3;
  const int sRow1 = sRow0 + 64;      // (tid+256)>>2

  for (int kt = 0; kt < 22; ++kt) {
    const int k0 = kt * 32;

    // ---- stage A tile (fp32 -> bf16, 2 slots of 16B per thread) ----
#pragma unroll
    for (int i = 0; i < 2; ++i) {
      const int row = (i == 0) ? sRow0 : sRow1;
      const int gk  = k0 + sKb * 8;
      float4 f0 = {0, 0, 0, 0}, f1 = {0, 0, 0, 0};
      const float* ap = A + (size_t)(bm * 128 + row) * 700 + gk;
      if (gk + 4 <= 700) f0 = *reinterpret_cast<const float4*>(ap);
      if (gk + 8 <= 700) f1 = *reinterpret_cast<const float4*>(ap + 4);
      int4 pk;
      pk.x = pack2(f0.x, f0.y); pk.y = pack2(f0.z, f0.w);
      pk.z = pack2(f1.x, f1.y); pk.w = pack2(f1.z, f1.w);
      As[row * 4 + (sKb ^ ((row >> 2) & 3))] = pk;
    }
    // ---- stage B^T tile (already bf16, 2 x 16B per thread) ----
#pragma unroll
    for (int i = 0; i < 2; ++i) {
      const int col = (i == 0) ? sRow0 : sRow1;
      const int4 v = *reinterpret_cast<const int4*>(Wt + (size_t)col * KP + k0 + sKb * 8);
      Bs[col * 4 + (sKb ^ ((col >> 2) & 3))] = v;
    }
    __syncthreads();

    // ---- fragments + MFMA ----
    bf16x8 af[4], bfr[4];
#pragma unroll
    for (int i = 0; i < 4; ++i) {
      const int row = wm * 64 + i * 16 + l16;
      af[i] = *reinterpret_cast<const bf16x8*>(&As[row * 4 + kbA]);
    }
#pragma unroll
    for (int n = 0; n < 4; ++n) {
      const int col = wn * 64 + n * 16 + l16;
      bfr[n] = *reinterpret_cast<const bf16x8*>(&Bs[col * 4 + kbA]);
    }
#pragma unroll
    for (int i = 0; i < 4; ++i)
#pragma unroll
      for (int n = 0; n < 4; ++n)
        acc[i][n] = __builtin_amdgcn_mfma_f32_16x16x32_bf16(af[i], bfr[n], acc[i][n], 0, 0, 0);
    __syncthreads();
  }

  // ---- epilogue: D row = (lane>>4)*4 + reg, col = lane&15 ----
  const int rbase = bm * 128 + wm * 64 + lkb * 4;
#pragma unroll
  for (int i = 0; i < 4; ++i) {
#pragma unroll
    for (int n = 0; n < 4; ++n) {
      const int gcol = wn * 64 + n * 16 + l16;
#pragma unroll
      for (int r = 0; r < 4; ++r)
        H[(size_t)(rbase + i * 16 + r) * 128 + gcol] = acc[i][n][r];
    }
  }
}

// =====================  segmented scan (3 phases)  =====================
// state v_t=(S_t,M_t); v_t = A v_{t-1} + [h[t-1],0], A=[[a,0],[1-b,b]]
// outputs: syn[t]=S_t, mem[t]=M_t, v_0 = 0.

// Phase A: per-segment local scan from zero -> endpoint e_j = (S,M) after LSEG steps
__global__ __launch_bounds__(64) void scan_ep(
    const float* __restrict__ h, float2* __restrict__ ep,
    const float* __restrict__ alpha, const float* __restrict__ beta)
{
  const int seg  = blockIdx.x & (NSEG - 1);
  const int half = (blockIdx.x >> 4) & 1;
  const int b    = blockIdx.x >> 5;
  const int o    = half * 64 + threadIdx.x;
  const float a = alpha[o], bt = beta[o], omb = 1.0f - bt;
  const float* hp = h + ((size_t)b * Tn + seg * LSEG) * On + o;
  float S = 0.f, M = 0.f;
  float buf[4];
#pragma unroll
  for (int d = 0; d < 4; ++d) buf[d] = hp[d * On];
  for (int tb = 0; tb < LSEG; tb += 4) {
#pragma unroll
    for (int d = 0; d < 4; ++d) {
      const float x = buf[d];
      if (tb + d + 4 < LSEG) buf[d] = hp[(tb + d + 4) * On];
      M = fmaf(bt, M, omb * S);   // uses OLD S
      S = fmaf(a, S, x);
    }
  }
  ep[(size_t)seg * BO + b * On + o] = make_float2(S, M);
}

// Phase B: combine endpoints sequentially; overwrite ep[j] with P_j = state at
// segment-j start. A^L = [[aL,0],[cL,bL]], coefficients built by stable iteration.
__global__ __launch_bounds__(256) void scan_prefix(
    float2* __restrict__ ep,
    const float* __restrict__ alpha, const float* __restrict__ beta)
{
  const int idx = blockIdx.x * 256 + threadIdx.x;   // b*128 + o
  const int o = idx & (On - 1);
  const float a = alpha[o], bt = beta[o], omb = 1.0f - bt;
  float aL = 1.f, bL = 1.f, cL = 0.f;
#pragma unroll
  for (int i = 0; i < LSEG; ++i) {
    cL = fmaf(bt, cL, omb * aL);
    aL *= a; bL *= bt;
  }
  float S = 0.f, M = 0.f;
  for (int j = 0; j < NSEG; ++j) {
    const float2 e = ep[(size_t)j * BO + idx];
    ep[(size_t)j * BO + idx] = make_float2(S, M);     // P_j
    const float nS = fmaf(aL, S, e.x);
    M = fmaf(bL, M, fmaf(cL, S, e.y));                // uses OLD S
    S = nS;
  }
}

// Phase C: exact per-segment scan with init P_j; in-place h -> syn, plus mem.
__global__ __launch_bounds__(64) void scan_seg(
    float* __restrict__ syn, float* __restrict__ mem, const float2* __restrict__ ep,
    const float* __restrict__ alpha, const float* __restrict__ beta)
{
  const int seg  = blockIdx.x & (NSEG - 1);
  const int half = (blockIdx.x >> 4) & 1;
  const int b    = blockIdx.x >> 5;
  const int o    = half * 64 + threadIdx.x;
  const float a = alpha[o], bt = beta[o], omb = 1.0f - bt;
  const float2 v0 = ep[(size_t)seg * BO + b * On + o];
  float S = v0.x, M = v0.y;
  float* hp = syn + ((size_t)b * Tn + seg * LSEG) * On + o;  // holds h, becomes S
  float* mp = mem + ((size_t)b * Tn + seg * LSEG) * On + o;
  float buf[4];
#pragma unroll
  for (int d = 0; d < 4; ++d) buf[d] = hp[d * On];
  for (int tb = 0; tb < LSEG; tb += 4) {
#pragma unroll
    for (int d = 0; d < 4; ++d) {
      const int t = tb + d;
      const float x = buf[d];
      if (t + 4 < LSEG) buf[d] = hp[(t + 4) * On];
      hp[t * On] = S;
      mp[t * On] = M;
      M = fmaf(bt, M, omb * S);   // uses OLD S
      S = fmaf(a, S, x);
    }
  }
}

// ---- fallback single-pass scan (used only if ws_size is too small) ----
__global__ __launch_bounds__(64) void scan_k(
    float* __restrict__ syn, float* __restrict__ mem,
    const float* __restrict__ alpha, const float* __restrict__ beta)
{
  const int b = blockIdx.x >> 1;
  const int o = ((blockIdx.x & 1) << 6) + threadIdx.x;
  const float a   = alpha[o];
  const float bt  = beta[o];
  const float omb = 1.0f - bt;
  float* hp = syn + (size_t)b * Tn * On + o;
  float* mp = mem + (size_t)b * Tn * On + o;
  float S = 0.f, M = 0.f;
  float buf[8];
#pragma unroll
  for (int d = 0; d < 8; ++d) buf[d] = hp[d * On];
  for (int tb = 0; tb < Tn; tb += 8) {
#pragma unroll
    for (int d = 0; d < 8; ++d) {
      const int t = tb + d;
      const float h_t = buf[d];
      if (t + 8 < Tn) buf[d] = hp[(t + 8) * On];
      hp[t * On] = S;
      mp[t * On] = M;
      const float nS = fmaf(a, S, h_t);
      M = fmaf(bt, M, omb * S);
      S = nS;
    }
  }
}

extern "C" void kernel_launch(void* const* d_in, const int* in_sizes, int n_in,
                              void* d_out, int out_size, void* d_ws, size_t ws_size,
                              hipStream_t stream) {
  const float* inputs = (const float*)d_in[0];   // (128,512,700)
  const float* w      = (const float*)d_in[1];   // (700,128)
  const float* alpha  = (const float*)d_in[2];   // (1,128)
  const float* beta   = (const float*)d_in[3];   // (1,128)

  float* syn = (float*)d_out;                    // first 8M floats
  float* mem = syn + (size_t)Bsz * Tn * On;      // next 8M floats
  ushort* w_t = (ushort*)mem;                    // 180 KB temp in mem region,
                                                 // consumed by gemm before scan writes

  prep_wt<<<(On * KP + 255) / 256, 256, 0, stream>>>(w, w_t);
  gemm_h<<<Mn / 128, 256, 0, stream>>>(inputs, w_t, syn);

  const size_t ep_bytes = (size_t)NSEG * BO * sizeof(float2);  // 2 MB
  if (ws_size >= ep_bytes) {
    float2* ep = (float2*)d_ws;
    scan_ep<<<Bsz * 2 * NSEG, 64, 0, stream>>>(syn, ep, alpha, beta);
    scan_prefix<<<BO / 256, 256, 0, stream>>>(ep, alpha, beta);
    scan_seg<<<Bsz * 2 * NSEG, 64, 0, stream>>>(syn, mem, ep, alpha, beta);
  } else {
    scan_k<<<Bsz * 2, 64, 0, stream>>>(syn, mem, alpha, beta);
  }
}

// Round 3
// 70.345 us; speedup vs baseline: 2.8431x; 1.1215x over previous
//
#include <hip/hip_runtime.h>
#include <hip/hip_bf16.h>
#include <stdint.h>

#define Bsz 128
#define Tn  512
#define In  700
#define On  128
#define Mn  (Bsz * Tn)   // 65536
#define KP  704          // K padded to multiple of 32
#define NSEG 16
#define LSEG 32          // Tn / NSEG
#define BO   (Bsz * On)  // 16384 chains
#define NKT  22          // K tiles of 32

using bf16x8 = __attribute__((ext_vector_type(8))) short;
using f32x4  = __attribute__((ext_vector_type(4))) float;

__device__ __forceinline__ uint32_t f2bf(float f) {
  union { float f; uint32_t u; } v; v.f = f;
  return (v.u + 0x7fffu + ((v.u >> 16) & 1u)) >> 16;   // RNE
}

__device__ __forceinline__ bf16x8 cvt8(float4 f0, float4 f1) {
  bf16x8 r;
  r[0] = (short)f2bf(f0.x); r[1] = (short)f2bf(f0.y);
  r[2] = (short)f2bf(f0.z); r[3] = (short)f2bf(f0.w);
  r[4] = (short)f2bf(f1.x); r[5] = (short)f2bf(f1.y);
  r[6] = (short)f2bf(f1.z); r[7] = (short)f2bf(f1.w);
  return r;
}

// async global->LDS, 16B per lane; LDS dest = wave-uniform base + lane*16
__device__ __forceinline__ void gload16(const void* g, void* l) {
  __builtin_amdgcn_global_load_lds(
      (__attribute__((address_space(1))) void*)g,
      (__attribute__((address_space(3))) void*)l, 16, 0, 0);
}

// ---- prep: w (700x128 f32, k-major) -> w_t (128 x 704 bf16, zero-padded K) ----
__global__ void prep_wt(const float* __restrict__ w, ushort* __restrict__ w_t) {
  int idx = blockIdx.x * 256 + threadIdx.x;
  if (idx >= On * KP) return;
  int col = idx / KP, k = idx - col * KP;
  float v = (k < In) ? w[(size_t)k * On + col] : 0.0f;
  w_t[(size_t)col * KP + k] = (ushort)f2bf(v);
}

// ---- GEMM + fused per-segment local scan (phase A) ----
// h[m][n] = sum_k A[m][k]*w[k][n]; each block = 128 rows (one b, 4 segments) x all 128 cols.
union SMU {
  struct {
    uint32_t A[2][4096];   // fp32 tile 128 rows x 8 slots x 16B, src-swizzled (16KB each)
    uint32_t B[2][2048];   // bf16 tile 128 cols x 4 slots x 16B, src-swizzled (8KB each)
  } db;
  float sc[128 * 132];     // 66 KB acc/scan buffer (pad 132 vs 128)
};

__global__ __launch_bounds__(256, 2) void gemm_h(
    const float* __restrict__ A,    // 65536 x 700 f32
    const ushort* __restrict__ Wt,  // 128 x 704 bf16 (transposed w)
    float* __restrict__ H,          // 65536 x 128 f32 (h -> later syn)
    float2* __restrict__ ep,        // [NSEG][BO] endpoints (may be null)
    const float* __restrict__ alpha, const float* __restrict__ beta)
{
  __shared__ __align__(16) SMU sm;

  const int tid  = threadIdx.x;
  const int bm   = blockIdx.x;        // 512 blocks over M
  const int lane = tid & 63;
  const int wid  = tid >> 6;          // 4 waves, 2x2 wave grid (64x64 each)
  const int wm   = wid >> 1, wn = wid & 1;
  const int l16  = lane & 15, lkb = lane >> 4;

  f32x4 acc[4][4];
#pragma unroll
  for (int i = 0; i < 4; ++i)
#pragma unroll
    for (int n = 0; n < 4; ++n) acc[i][n] = (f32x4){0.f, 0.f, 0.f, 0.f};

  // ---------- staging (async, source-side swizzle) ----------
  auto stage = [&](int bi, int kt) {
    const int k0 = kt * 32;
    // A: 128 rows x 32 k fp32 = 16KB = 4 wave-issues of 16B/lane
#pragma unroll
    for (int is = 0; is < 4; ++is) {
      const int q   = is * 256 + wid * 64 + lane;   // linear 16B slot
      const int row = q >> 3, sl = q & 7;
      int gk = k0 + ((sl ^ (row & 7)) << 2);        // inverse-swizzled source k
      if (gk >= In) gk = k0;                        // clamp; B is zero at k>=700
      gload16(A + (size_t)(bm * 128 + row) * In + gk,
              &sm.db.A[bi][is * 1024 + wid * 256]);
    }
    // B: 128 cols x 32 k bf16 = 8KB = 2 wave-issues
#pragma unroll
    for (int is = 0; is < 2; ++is) {
      const int q   = is * 256 + wid * 64 + lane;
      const int col = q >> 2, sl = q & 3;
      const int ks  = sl ^ ((col >> 1) & 3);
      gload16(Wt + (size_t)col * KP + k0 + ks * 8,
              &sm.db.B[bi][is * 1024 + wid * 256]);
    }
  };

  int cur = 0;
  stage(0, 0);
  __syncthreads();   // compiler drains vmcnt here

  for (int kt = 0; kt < NKT; ++kt) {
    if (kt + 1 < NKT) stage(cur ^ 1, kt + 1);   // prefetch overlaps below

    const float4* Af = (const float4*)sm.db.A[cur];   // idx = row*8 + slot
    const bf16x8* Bf = (const bf16x8*)sm.db.B[cur];   // idx = col*4 + slot

    bf16x8 af[4], bfr[4];
#pragma unroll
    for (int i = 0; i < 4; ++i) {
      const int row = wm * 64 + i * 16 + l16;
      const int s0  = (lkb * 2) ^ (row & 7);
      const int s1  = (lkb * 2 + 1) ^ (row & 7);
      af[i] = cvt8(Af[row * 8 + s0], Af[row * 8 + s1]);
    }
#pragma unroll
    for (int n = 0; n < 4; ++n) {
      const int col = wn * 64 + n * 16 + l16;
      bfr[n] = Bf[col * 4 + (lkb ^ ((col >> 1) & 3))];
    }
#pragma unroll
    for (int i = 0; i < 4; ++i)
#pragma unroll
      for (int n = 0; n < 4; ++n)
        acc[i][n] = __builtin_amdgcn_mfma_f32_16x16x32_bf16(af[i], bfr[n], acc[i][n], 0, 0, 0);

    __syncthreads();   // drains this tile's prefetch + protects dbuf swap
    cur ^= 1;
  }

  // ---------- epilogue: acc -> LDS (t-major, pad 132) ----------
#pragma unroll
  for (int i = 0; i < 4; ++i)
#pragma unroll
    for (int n = 0; n < 4; ++n) {
      const int col = wn * 64 + n * 16 + l16;
#pragma unroll
      for (int r = 0; r < 4; ++r) {
        const int row = wm * 64 + i * 16 + lkb * 4 + r;
        sm.sc[row * 132 + col] = acc[i][n][r];
      }
    }
  __syncthreads();

  // coalesced float4 H write from LDS
  const size_t hbase = (size_t)bm * 128 * 128;
#pragma unroll
  for (int i2 = 0; i2 < 16; ++i2) {
    const int q = i2 * 256 + tid;
    const int row = q >> 5, v = q & 31;
    *(float4*)&H[hbase + row * 128 + v * 4] =
        *(const float4*)&sm.sc[row * 132 + v * 4];
  }

  // fused phase A: per-segment local scan from zero (4 segs x 128 cols = 512 chains)
  if (ep) {
    const int o = tid & 127;
    const float a = alpha[o], bt = beta[o], omb = 1.0f - bt;
    const int b = bm >> 2, seg0 = (bm & 3) * 4;
#pragma unroll
    for (int cc = 0; cc < 2; ++cc) {
      const int sl = (tid >> 7) + cc * 2;
      float S = 0.f, M = 0.f;
      const float* base = &sm.sc[(sl * 32) * 132 + o];
#pragma unroll
      for (int t = 0; t < 32; ++t) {
        const float x = base[t * 132];
        M = fmaf(bt, M, omb * S);   // uses OLD S
        S = fmaf(a, S, x);
      }
      ep[(size_t)(seg0 + sl) * BO + b * On + o] = make_float2(S, M);
    }
  }
}

// ---- Phase B: combine endpoints sequentially; ep[j] <- state at segment-j start ----
__global__ __launch_bounds__(256) void scan_prefix(
    float2* __restrict__ ep,
    const float* __restrict__ alpha, const float* __restrict__ beta)
{
  const int idx = blockIdx.x * 256 + threadIdx.x;   // b*128 + o
  const int o = idx & (On - 1);
  const float a = alpha[o], bt = beta[o], omb = 1.0f - bt;
  float aL = 1.f, bL = 1.f, cL = 0.f;
#pragma unroll
  for (int i = 0; i < LSEG; ++i) {
    cL = fmaf(bt, cL, omb * aL);
    aL *= a; bL *= bt;
  }
  float S = 0.f, M = 0.f;
  for (int j = 0; j < NSEG; ++j) {
    const float2 e = ep[(size_t)j * BO + idx];
    ep[(size_t)j * BO + idx] = make_float2(S, M);     // P_j
    const float nS = fmaf(aL, S, e.x);
    M = fmaf(bL, M, fmaf(cL, S, e.y));                // uses OLD S
    S = nS;
  }
}

// ---- Phase C: exact per-segment scan with init P_j; in-place h -> syn, plus mem ----
__global__ __launch_bounds__(256) void scan_seg(
    float* __restrict__ syn, float* __restrict__ mem, const float2* __restrict__ ep,
    const float* __restrict__ alpha, const float* __restrict__ beta)
{
  const int cid = blockIdx.x * 256 + threadIdx.x;   // ((b*NSEG+seg)*On + o)
  const int o   = cid & (On - 1);
  const int bs  = cid >> 7;
  const int seg = bs & (NSEG - 1), b = bs >> 4;
  const float a = alpha[o], bt = beta[o], omb = 1.0f - bt;
  const float2 v0 = ep[(size_t)seg * BO + b * On + o];
  float S = v0.x, M = v0.y;
  float* hp = syn + ((size_t)b * Tn + seg * LSEG) * On + o;  // holds h, becomes S
  float* mp = mem + ((size_t)b * Tn + seg * LSEG) * On + o;
  float buf[8];
#pragma unroll
  for (int d = 0; d < 8; ++d) buf[d] = hp[d * On];
  for (int tb = 0; tb < LSEG; tb += 8) {
#pragma unroll
    for (int d = 0; d < 8; ++d) {
      const int t = tb + d;
      const float x = buf[d];
      if (t + 8 < LSEG) buf[d] = hp[(t + 8) * On];
      hp[t * On] = S;
      mp[t * On] = M;
      M = fmaf(bt, M, omb * S);   // uses OLD S
      S = fmaf(a, S, x);
    }
  }
}

// ---- fallback single-pass scan (used only if ws_size is too small) ----
__global__ __launch_bounds__(64) void scan_k(
    float* __restrict__ syn, float* __restrict__ mem,
    const float* __restrict__ alpha, const float* __restrict__ beta)
{
  const int b = blockIdx.x >> 1;
  const int o = ((blockIdx.x & 1) << 6) + threadIdx.x;
  const float a = alpha[o], bt = beta[o], omb = 1.0f - bt;
  float* hp = syn + (size_t)b * Tn * On + o;
  float* mp = mem + (size_t)b * Tn * On + o;
  float S = 0.f, M = 0.f;
  float buf[8];
#pragma unroll
  for (int d = 0; d < 8; ++d) buf[d] = hp[d * On];
  for (int tb = 0; tb < Tn; tb += 8) {
#pragma unroll
    for (int d = 0; d < 8; ++d) {
      const int t = tb + d;
      const float h_t = buf[d];
      if (t + 8 < Tn) buf[d] = hp[(t + 8) * On];
      hp[t * On] = S;
      mp[t * On] = M;
      const float nS = fmaf(a, S, h_t);
      M = fmaf(bt, M, omb * S);
      S = nS;
    }
  }
}

extern "C" void kernel_launch(void* const* d_in, const int* in_sizes, int n_in,
                              void* d_out, int out_size, void* d_ws, size_t ws_size,
                              hipStream_t stream) {
  const float* inputs = (const float*)d_in[0];   // (128,512,700)
  const float* w      = (const float*)d_in[1];   // (700,128)
  const float* alpha  = (const float*)d_in[2];   // (1,128)
  const float* beta   = (const float*)d_in[3];   // (1,128)

  float* syn = (float*)d_out;                    // first 8M floats
  float* mem = syn + (size_t)Bsz * Tn * On;      // next 8M floats
  ushort* w_t = (ushort*)mem;                    // 180 KB temp in mem region,
                                                 // consumed by gemm before scan writes

  const size_t ep_bytes = (size_t)NSEG * BO * sizeof(float2);  // 2 MB
  float2* ep = (ws_size >= ep_bytes) ? (float2*)d_ws : nullptr;

  prep_wt<<<(On * KP + 255) / 256, 256, 0, stream>>>(w, w_t);
  gemm_h<<<Mn / 128, 256, 0, stream>>>(inputs, w_t, syn, ep, alpha, beta);

  if (ep) {
    scan_prefix<<<BO / 256, 256, 0, stream>>>(ep, alpha, beta);
    scan_seg<<<(Bsz * NSEG * On) / 256, 256, 0, stream>>>(syn, mem, ep, alpha, beta);
  } else {
    scan_k<<<Bsz * 2, 64, 0, stream>>>(syn, mem, alpha, beta);
  }
}

// Round 4
// 63.071 us; speedup vs baseline: 3.1710x; 1.1153x over previous
//
#include <hip/hip_runtime.h>
#include <hip/hip_bf16.h>
#include <stdint.h>

#define Bsz 128
#define Tn  512
#define In  700
#define On  128
#define Mn  (Bsz * Tn)   // 65536
#define KP  704          // K padded to multiple of 32
#define NSEG 16
#define LSEG 32          // Tn / NSEG
#define BO   (Bsz * On)  // 16384 chains
#define NKT  22          // K tiles of 32

using bf16x8 = __attribute__((ext_vector_type(8))) short;
using f32x4  = __attribute__((ext_vector_type(4))) float;

#define WAITVM(N) asm volatile("s_waitcnt vmcnt(" #N ")" ::: "memory")

__device__ __forceinline__ uint32_t f2bf(float f) {
  union { float f; uint32_t u; } v; v.f = f;
  return (v.u + 0x7fffu + ((v.u >> 16) & 1u)) >> 16;   // RNE
}

__device__ __forceinline__ bf16x8 cvt8(float4 f0, float4 f1) {
  bf16x8 r;
  r[0] = (short)f2bf(f0.x); r[1] = (short)f2bf(f0.y);
  r[2] = (short)f2bf(f0.z); r[3] = (short)f2bf(f0.w);
  r[4] = (short)f2bf(f1.x); r[5] = (short)f2bf(f1.y);
  r[6] = (short)f2bf(f1.z); r[7] = (short)f2bf(f1.w);
  return r;
}

// async global->LDS, 16B per lane; LDS dest = wave-uniform base + lane*16
__device__ __forceinline__ void gload16(const void* g, void* l) {
  __builtin_amdgcn_global_load_lds(
      (__attribute__((address_space(1))) void*)g,
      (__attribute__((address_space(3))) void*)l, 16, 0, 0);
}

// ---- prep: w (700x128 f32, k-major) -> w_t (128 x 704 bf16, zero-padded K) ----
__global__ void prep_wt(const float* __restrict__ w, ushort* __restrict__ w_t) {
  int idx = blockIdx.x * 256 + threadIdx.x;
  if (idx >= On * KP) return;
  int col = idx / KP, k = idx - col * KP;
  float v = (k < In) ? w[(size_t)k * On + col] : 0.0f;
  w_t[(size_t)col * KP + k] = (ushort)f2bf(v);
}

// ---- GEMM + fused per-segment local scan (phase A) ----
// 3-deep global_load_lds pipeline with counted vmcnt (loads stay in flight
// across raw s_barriers; never drain to 0 in the main loop).
union SMU {
  struct {
    uint32_t A[3][4096];   // 48 KB: fp32 tile 128 rows x 8 slots x 16B, src-swizzled
    uint32_t B[3][2048];   // 24 KB: bf16 tile 128 cols x 4 slots x 16B, src-swizzled
  } db;                    // 72 KB staging -> 2 blocks/CU
  float sc[128 * 132];     // 66 KB acc/scan buffer (pad 132 vs 128)
};

__global__ __launch_bounds__(256, 2) void gemm_h(
    const float* __restrict__ A,    // 65536 x 700 f32
    const ushort* __restrict__ Wt,  // 128 x 704 bf16 (transposed w)
    float* __restrict__ H,          // 65536 x 128 f32 (h -> later syn)
    float2* __restrict__ ep,        // [NSEG][BO] endpoints (may be null)
    const float* __restrict__ alpha, const float* __restrict__ beta)
{
  __shared__ __align__(16) SMU sm;

  const int tid  = threadIdx.x;
  const int bm   = blockIdx.x;        // 512 blocks over M
  const int lane = tid & 63;
  const int wid  = tid >> 6;          // 4 waves, 2x2 wave grid (64x64 each)
  const int wm   = wid >> 1, wn = wid & 1;
  const int l16  = lane & 15, lkb = lane >> 4;

  // load alpha/beta FIRST so no vmem op interleaves with the counted pipeline
  const int   o_ep = tid & 127;
  const float a_ep = alpha[o_ep];
  const float b_ep = beta[o_ep];

  f32x4 acc[4][4];
#pragma unroll
  for (int i = 0; i < 4; ++i)
#pragma unroll
    for (int n = 0; n < 4; ++n) acc[i][n] = (f32x4){0.f, 0.f, 0.f, 0.f};

  // ---------- staging (async, source-side swizzle); 6 loads per wave ----------
  auto stage = [&](int bi, int kt) {
    const int k0 = kt * 32;
    // A: 128 rows x 32 k fp32 = 16KB = 4 wave-issues of 16B/lane
#pragma unroll
    for (int is = 0; is < 4; ++is) {
      const int q   = is * 256 + wid * 64 + lane;   // linear 16B slot
      const int row = q >> 3, sl = q & 7;
      int gk = k0 + ((sl ^ (row & 7)) << 2);        // inverse-swizzled source k
      if (gk >= In) gk = k0;                        // clamp; Wt is zero at k>=700
      gload16(A + (size_t)(bm * 128 + row) * In + gk,
              &sm.db.A[bi][is * 1024 + wid * 256]);
    }
    // B: 128 cols x 32 k bf16 = 8KB = 2 wave-issues
#pragma unroll
    for (int is = 0; is < 2; ++is) {
      const int q   = is * 256 + wid * 64 + lane;
      const int col = q >> 2, sl = q & 3;
      const int ks  = sl ^ ((col >> 1) & 3);
      gload16(Wt + (size_t)col * KP + k0 + ks * 8,
              &sm.db.B[bi][is * 1024 + wid * 256]);
    }
  };

  // one K-tile: barrier (tile kt landed, via caller's WAITVM) -> frag reads ->
  // drain lgkm -> barrier (buf reusable) -> issue stage(kt+3) -> MFMA
  auto tile = [&](int kt, int cur) {
    __builtin_amdgcn_s_barrier();
    const float4* Af = (const float4*)sm.db.A[cur];   // idx = row*8 + slot
    const bf16x8* Bf = (const bf16x8*)sm.db.B[cur];   // idx = col*4 + slot
    bf16x8 af[4], bfr[4];
#pragma unroll
    for (int i = 0; i < 4; ++i) {
      const int row = wm * 64 + i * 16 + l16;
      const int s0  = (lkb * 2) ^ (row & 7);
      const int s1  = (lkb * 2 + 1) ^ (row & 7);
      af[i] = cvt8(Af[row * 8 + s0], Af[row * 8 + s1]);
    }
#pragma unroll
    for (int n = 0; n < 4; ++n) {
      const int col = wn * 64 + n * 16 + l16;
      bfr[n] = Bf[col * 4 + (lkb ^ ((col >> 1) & 3))];
    }
    asm volatile("s_waitcnt lgkmcnt(0)" ::: "memory");
    __builtin_amdgcn_s_barrier();
    if (kt + 3 < NKT) stage(cur, kt + 3);   // overwrite just-consumed buffer
#pragma unroll
    for (int i = 0; i < 4; ++i)
#pragma unroll
      for (int n = 0; n < 4; ++n)
        acc[i][n] = __builtin_amdgcn_mfma_f32_16x16x32_bf16(af[i], bfr[n], acc[i][n], 0, 0, 0);
  };

  stage(0, 0); stage(1, 1); stage(2, 2);    // 18 loads/wave in flight
  {
    int cur = 0;
    for (int kt = 0; kt < NKT - 2; ++kt) {  // kt = 0..19: 3 tiles outstanding
      WAITVM(12);
      tile(kt, cur);
      cur = (cur == 2) ? 0 : cur + 1;
    }
    WAITVM(6);  tile(NKT - 2, (NKT - 2) % 3);   // 2 tiles outstanding
    WAITVM(0);  tile(NKT - 1, (NKT - 1) % 3);   // last
  }

  // ---------- epilogue: acc -> LDS (t-major, pad 132) ----------
#pragma unroll
  for (int i = 0; i < 4; ++i)
#pragma unroll
    for (int n = 0; n < 4; ++n) {
      const int col = wn * 64 + n * 16 + l16;
#pragma unroll
      for (int r = 0; r < 4; ++r) {
        const int row = wm * 64 + i * 16 + lkb * 4 + r;
        sm.sc[row * 132 + col] = acc[i][n][r];
      }
    }
  __syncthreads();

  // coalesced float4 H write from LDS
  const size_t hbase = (size_t)bm * 128 * 128;
#pragma unroll
  for (int i2 = 0; i2 < 16; ++i2) {
    const int q = i2 * 256 + tid;
    const int row = q >> 5, v = q & 31;
    *(float4*)&H[hbase + row * 128 + v * 4] =
        *(const float4*)&sm.sc[row * 132 + v * 4];
  }

  // fused phase A: per-segment local scan from zero (4 segs x 128 cols = 512 chains)
  if (ep) {
    const float a = a_ep, bt = b_ep, omb = 1.0f - b_ep;
    const int b = bm >> 2, seg0 = (bm & 3) * 4;
#pragma unroll
    for (int cc = 0; cc < 2; ++cc) {
      const int sl = (tid >> 7) + cc * 2;
      float S = 0.f, M = 0.f;
      const float* base = &sm.sc[(sl * 32) * 132 + o_ep];
#pragma unroll
      for (int t = 0; t < 32; ++t) {
        const float x = base[t * 132];
        M = fmaf(bt, M, omb * S);   // uses OLD S
        S = fmaf(a, S, x);
      }
      ep[(size_t)(seg0 + sl) * BO + b * On + o_ep] = make_float2(S, M);
    }
  }
}

// ---- Phase B+C fused: per-thread prefix over ep[0..seg-1], then exact segment
// scan with that init; in-place h -> syn, plus mem ----
__global__ __launch_bounds__(256) void scan_seg(
    float* __restrict__ syn, float* __restrict__ mem, const float2* __restrict__ ep,
    const float* __restrict__ alpha, const float* __restrict__ beta)
{
  const int cid = blockIdx.x * 256 + threadIdx.x;   // ((b*NSEG+seg)*On + o)
  const int o   = cid & (On - 1);
  const int bs  = cid >> 7;
  const int seg = bs & (NSEG - 1), b = bs >> 4;
  const float a = alpha[o], bt = beta[o], omb = 1.0f - bt;

  // A^L coefficients (stable iteration)
  float aL = 1.f, bL = 1.f, cL = 0.f;
#pragma unroll
  for (int i = 0; i < LSEG; ++i) {
    cL = fmaf(bt, cL, omb * aL);
    aL *= a; bL *= bt;
  }
  // prefix over preceding segment endpoints (wave-uniform trip count)
  float S = 0.f, M = 0.f;
  for (int j = 0; j < seg; ++j) {
    const float2 e = ep[(size_t)j * BO + b * On + o];
    const float nS = fmaf(aL, S, e.x);
    M = fmaf(bL, M, fmaf(cL, S, e.y));   // uses OLD S
    S = nS;
  }

  float* hp = syn + ((size_t)b * Tn + seg * LSEG) * On + o;  // holds h, becomes S
  float* mp = mem + ((size_t)b * Tn + seg * LSEG) * On + o;
  float buf[8];
#pragma unroll
  for (int d = 0; d < 8; ++d) buf[d] = hp[d * On];
  for (int tb = 0; tb < LSEG; tb += 8) {
#pragma unroll
    for (int d = 0; d < 8; ++d) {
      const int t = tb + d;
      const float x = buf[d];
      if (t + 8 < LSEG) buf[d] = hp[(t + 8) * On];
      hp[t * On] = S;
      mp[t * On] = M;
      M = fmaf(bt, M, omb * S);   // uses OLD S
      S = fmaf(a, S, x);
    }
  }
}

// ---- fallback single-pass scan (used only if ws_size is too small) ----
__global__ __launch_bounds__(64) void scan_k(
    float* __restrict__ syn, float* __restrict__ mem,
    const float* __restrict__ alpha, const float* __restrict__ beta)
{
  const int b = blockIdx.x >> 1;
  const int o = ((blockIdx.x & 1) << 6) + threadIdx.x;
  const float a = alpha[o], bt = beta[o], omb = 1.0f - bt;
  float* hp = syn + (size_t)b * Tn * On + o;
  float* mp = mem + (size_t)b * Tn * On + o;
  float S = 0.f, M = 0.f;
  float buf[8];
#pragma unroll
  for (int d = 0; d < 8; ++d) buf[d] = hp[d * On];
  for (int tb = 0; tb < Tn; tb += 8) {
#pragma unroll
    for (int d = 0; d < 8; ++d) {
      const int t = tb + d;
      const float h_t = buf[d];
      if (t + 8 < Tn) buf[d] = hp[(t + 8) * On];
      hp[t * On] = S;
      mp[t * On] = M;
      const float nS = fmaf(a, S, h_t);
      M = fmaf(bt, M, omb * S);
      S = nS;
    }
  }
}

extern "C" void kernel_launch(void* const* d_in, const int* in_sizes, int n_in,
                              void* d_out, int out_size, void* d_ws, size_t ws_size,
                              hipStream_t stream) {
  const float* inputs = (const float*)d_in[0];   // (128,512,700)
  const float* w      = (const float*)d_in[1];   // (700,128)
  const float* alpha  = (const float*)d_in[2];   // (1,128)
  const float* beta   = (const float*)d_in[3];   // (1,128)

  float* syn = (float*)d_out;                    // first 8M floats
  float* mem = syn + (size_t)Bsz * Tn * On;      // next 8M floats
  ushort* w_t = (ushort*)mem;                    // 180 KB temp in mem region,
                                                 // consumed by gemm before scan writes

  const size_t ep_bytes = (size_t)NSEG * BO * sizeof(float2);  // 2 MB
  float2* ep = (ws_size >= ep_bytes) ? (float2*)d_ws : nullptr;

  prep_wt<<<(On * KP + 255) / 256, 256, 0, stream>>>(w, w_t);
  gemm_h<<<Mn / 128, 256, 0, stream>>>(inputs, w_t, syn, ep, alpha, beta);

  if (ep) {
    scan_seg<<<(Bsz * NSEG * On) / 256, 256, 0, stream>>>(syn, mem, ep, alpha, beta);
  } else {
    scan_k<<<Bsz * 2, 64, 0, stream>>>(syn, mem, alpha, beta);
  }
}